// Round 15
// baseline (181.393 us; speedup 1.0000x reference)
//
#include <hip/hip_runtime.h>

typedef unsigned short u16;
typedef unsigned int   u32;

#define NB   16      // batch
#define NC   128     // channels
#define NPIX 1024    // 32*32
#define NH   4       // heads
#define DH   32      // dim head

typedef __attribute__((ext_vector_type(8))) short short8;
typedef __attribute__((ext_vector_type(4))) float f32x4;
typedef __attribute__((ext_vector_type(8))) _Float16 half8;

#define XROWS 1152   // 64 guard + 1024 + 64 guard rows per batch in xTp

__device__ __forceinline__ float bf2f(u16 u) {
    return __uint_as_float(((u32)u) << 16);
}
__device__ __forceinline__ u16 f2bf(float f) {
    u32 u = __float_as_uint(f);
    u32 r = (u + 0x7fffu + ((u >> 16) & 1u)) >> 16;
    return (u16)r;
}
__device__ __forceinline__ u16 f2h(float f) {
    _Float16 h = (_Float16)f;
    u16 r; __builtin_memcpy(&r, &h, 2); return r;
}
__device__ __forceinline__ float h2f(u16 u) {
    _Float16 h; __builtin_memcpy(&h, &u, 2); return (float)h;
}
__device__ __forceinline__ int pk_h2(float a, float b) {
    auto h = __builtin_amdgcn_cvt_pkrtz(a, b);   // __fp16 ext_vector(2)
    int r; __builtin_memcpy(&r, &h, 4); return r;
}
// dtype-agnostic loads: isf=1 -> fp32 data, isf=0 -> bf16 data
__device__ __forceinline__ float loadf(const void* p, int i, int isf) {
    return isf ? ((const float*)p)[i] : bf2f(((const u16*)p)[i]);
}
__device__ __forceinline__ float4 load4(const void* p, int i4, int isf) {
    if (isf) return ((const float4*)p)[i4];
    ushort4 u = ((const ushort4*)p)[i4];
    return make_float4(bf2f(u.x), bf2f(u.y), bf2f(u.z), bf2f(u.w));
}
// Per-wave dtype self-detect (replaces detect_kernel dispatch).
// fp32 N(0,1) data: the 32 low-mantissa halfwords in x[0..63] hit exp>=134
// with P~0.48 each (P(no hit)=0.52^32~8e-10, identical for every wave since
// all read the same words). bf16 N(0,1): |x|<128 -> exp<134 always.
__device__ __forceinline__ int detect_isf(const void* x) {
    const u16* p = (const u16*)x;
    u16 v = p[threadIdx.x & 63];
    int e = (v >> 7) & 0xFF;
    unsigned long long m = __ballot(e >= 134);
    return m != 0ull ? 1 : 0;
}

// ---------------------------------------------------------------------------
// prep_all: fused prep. 1D grid of 1024 blocks (r14 coalesced weight read):
//   [0,192):    WtF  (192 blocks x 256 = 49,152 (j,co,ci); 9 taps each)
//   [192,256):  WfF  (16,384 elements, k-permuted — r13)
//   [256,768):  xTp transpose + guard zeroing (8 pixg x 4 cig x 16 b)
//   [768,1024): biasC fragment-order gather (16 nt x 16 mt)
// ---------------------------------------------------------------------------
__global__ __launch_bounds__(256) void prep_all(
        const void* __restrict__ x,
        const void* __restrict__ w0, const void* __restrict__ w1,
        const void* __restrict__ w2, const void* __restrict__ ow,
        const int* __restrict__ rel, const void* __restrict__ table,
        u16* __restrict__ Wt, u16* __restrict__ Wf, u16* __restrict__ xTp,
        u16* __restrict__ biasT, float* __restrict__ stats) {
    __shared__ __align__(16) u32 smem_u[4160];   // 16,640 B union
    int isf = detect_isf(x);
    int bid = blockIdx.x;
    int t = threadIdx.x;

    if (bid < 192) {
        // ---- WtF: coalesced 9-tap read per (j,co,ci) + stats zeroing ----
        if (bid == 0 && t < 96) stats[t] = 0.f;
        int g = bid * 256 + t;            // 0..49151
        int j  = g >> 14;                 // 0..2
        int cc = g & 16383;
        int co = cc >> 7, ci = cc & 127;
        const void* w = (j == 0) ? w0 : ((j == 1) ? w1 : w2);
        int coh = (co >> 6) & 1, wm = (co >> 5) & 1;
        int mt  = (co >> 4) & 1, l16 = co & 15;
        int ks  = (ci >> 5) & 3, q  = (ci >> 3) & 3, e = ci & 7;
        int dstbase = (coh * 2 + wm) * 4096 + ks * 1024 + mt * 512
                    + (q * 16 + l16) * 8 + e;
        int src0 = (co * 128 + ci) * 9;   // 9 contiguous floats follow
#pragma unroll
        for (int tap = 0; tap < 9; ++tap) {
            float v = loadf(w, src0 + tap, isf);
            Wt[(j * 9 + tap) * 16384 + dstbase] = f2bf(v);
        }
    } else if (bid < 256) {
        // ---- WfF (k-permuted for attfB, r13) ----
        int i2 = (bid - 192) * 256 + t;   // 0..16383
        int co = i2 >> 7, k = i2 & 127;
        int zc = (co >> 6) & 1, wm = (co >> 5) & 1;
        int mt = (co >> 4) & 1, l16 = co & 15;
        int ks = k >> 5, c = k & 31;
        // inverse of pi: channel c -> fragment slot (qf, ef)
        int qf, ef;
        if (c < 16) { qf = c >> 2;        ef = c & 3; }
        else        { qf = (c - 16) >> 2; ef = 4 + ((c - 16) & 3); }
        int dst = (zc * 2 + wm) * 4096 + ks * 1024 + mt * 512
                + (qf * 16 + l16) * 8 + ef;
        Wf[dst] = f2h(loadf(ow, i2, isf));
    } else if (bid < 768) {
        // ---- xTp transpose + guard zeroing (proven prep_x) ----
        float* tile = (float*)smem_u;            // 32*129 floats
        int b2 = bid - 256;
        int pixg = b2 & 7, cig = (b2 >> 3) & 3, b = b2 >> 5;

        if (pixg == 0 || pixg == 7) {
            int row = (pixg == 0 ? 0 : 1088) + (t >> 2);
            int seg = t & 3;
            size_t dst = ((size_t)(b * XROWS + row)) * 128 + cig * 32 + seg * 8;
            *(uint4*)&xTp[dst] = make_uint4(0, 0, 0, 0);
        }

        int ci = t >> 3, px0 = (t & 7) * 16;
        int base = b * (NC * NPIX) + (cig * 32 + ci) * NPIX + pixg * 128 + px0;
#pragma unroll
        for (int u = 0; u < 4; ++u) {
            float4 v = load4(x, (base >> 2) + u, isf);
            float* d = &tile[ci * 129 + px0 + u * 4];
            d[0] = v.x; d[1] = v.y; d[2] = v.z; d[3] = v.w;
        }
        __syncthreads();
#pragma unroll
        for (int u = 0; u < 2; ++u) {
            int c = t + u * 256;
            int pix = c >> 2, seg = c & 3;
            u16 tmp[8];
#pragma unroll
            for (int e = 0; e < 8; ++e)
                tmp[e] = f2bf(tile[(seg * 8 + e) * 129 + pix]);
            size_t dst = ((size_t)(b * XROWS + 64 + pixg * 128 + pix)) * 128
                       + cig * 32 + seg * 8;
            *(ushort4*)&xTp[dst] =
                make_ushort4(tmp[0], tmp[1], tmp[2], tmp[3]);
            *(ushort4*)&xTp[dst + 4] =
                make_ushort4(tmp[4], tmp[5], tmp[6], tmp[7]);
        }
    } else {
        // ---- biasC fragment-order gather; one float4 per (n,m) pair ----
        int* rl = (int*)smem_u;                  // 64*65 ints
        int b2 = bid - 768;
        int nt = b2 & 15, mt = b2 >> 4;

#pragma unroll
        for (int c = 0; c < 16; ++c) {
            int i = t + c * 256;              // 4096
            int r = i >> 6, cc = i & 63;      // r=n-local, cc=m-local
            rl[r * 65 + cc] = rel[(size_t)(nt * 64 + r) * 1024 + mt * 64 + cc];
        }
        __syncthreads();

#pragma unroll
        for (int c = 0; c < 16; ++c) {
            int wdx = t + c * 256;            // 0..4095
            int r     = wdx & 3;
            int lane  = (wdx >> 2) & 63;
            int fragl = wdx >> 8;             // 0..15
            int n16l  = fragl >> 2;           // 0..3
            int m16l  = fragl & 3;            // 0..3
            int n_loc = n16l * 16 + (lane & 15);
            int m_loc = m16l * 16 + ((lane >> 4) << 2) + r;
            int ri = rl[n_loc * 65 + m_loc];
            float4 tv = load4(table, ri, isf);   // all 4 heads (NH=4)
            float tvh[4] = {tv.x, tv.y, tv.z, tv.w};
            size_t off = ((size_t)((nt * 4 + n16l) * 64 + (mt * 4 + m16l))
                          << 8) + lane * 4 + r;
#pragma unroll
            for (int h = 0; h < NH; ++h)
                biasT[((size_t)h << 20) + off] = f2bf(tvh[h]);
        }
    }
}

// ---------------------------------------------------------------------------
// conv6: MFMA implicit-GEMM 3x3 conv, fragment-order weights (r6), convF
// output (r12). Round 15: T5 s_setprio(1) around the 8-MFMA clusters —
// conv6 has ZERO K-loop barriers (unlike m190's null-case lockstep GEMM):
// after the single staging barrier its 12 waves/CU free-run at staggered
// {ds_read -> MFMA} phases, the m191 regime where prio arbitration pays.
// Grid: (2coh x 8pt, 16 b, 3 j) = 768 blocks = 3 blocks/CU.
// ---------------------------------------------------------------------------
__global__ __launch_bounds__(256) void conv6_kernel(
        const u16* __restrict__ xTp, const u16* __restrict__ Wt,
        u16* __restrict__ conv_out, float* __restrict__ stats) {
    __shared__ __align__(16) u16 Xh[194 * 128];   // 49,664 B

    int t = threadIdx.x;
    int bx = blockIdx.x, b = blockIdx.y, j = blockIdx.z;
    int pt = bx >> 1, coh = bx & 1;
    int p0 = pt * 128;
    int w = t >> 6, lane = t & 63;
    int q = lane >> 4, l16 = lane & 15;
    int pixbase = (w >> 1) * 64;

    const u16* xb  = xTp + ((size_t)b * XROWS + 64) * 128;  // row 0 = pixel 0
    // fragment-order weight base for this wave: + tap*16384 + ks*1024 + mt*512
    const u16* wrb = Wt + (size_t)(j * 9) * 16384
                   + (coh * 2 + (w & 1)) * 4096 + lane * 8;

    // ---- prologue: issue tap-0 weight loads (before staging, no dep) ----
    short8 awA[2][4], awB[2][4];      // [mt][ks] double buffer
#pragma unroll
    for (int ks = 0; ks < 4; ++ks) {
        awA[0][ks] = *(const short8*)(wrb + ks * 1024);
        awA[1][ks] = *(const short8*)(wrb + ks * 1024 + 512);
    }

    // ---- stage Xh rows [p0-33, p0+161), unconditional (guard rows) ----
#pragma unroll
    for (int k = 0; k < 13; ++k) {
        int c = t + k * 256;
        if (c < 194 * 16) {
            int row = c >> 4, seg = c & 15;
            int pg = p0 - 33 + row;
            uint4 v = *(const uint4*)(xb + (size_t)pg * 128 + seg * 8);
            *(uint4*)&Xh[row * 128 + ((seg + row) & 15) * 8] = v;
        }
    }
    __syncthreads();     // the only barrier in the kernel

    f32x4 acc[2][4];
#pragma unroll
    for (int mt = 0; mt < 2; ++mt)
#pragma unroll
        for (int nt = 0; nt < 4; ++nt) acc[mt][nt] = (f32x4)0.f;

#pragma unroll
    for (int tap = 0; tap < 9; ++tap) {
        const int dy = tap / 3, dx = tap % 3;       // compile-time (unrolled)
        bool inv_e = (dx == 0) && (l16 == 0);    // nt even: px%32 == l16
        bool inv_o = (dx == 2) && (l16 == 15);   // nt odd:  px%32 == 16+l16
        int rbase = pixbase + dy * 32 + dx + l16;

        // prefetch tap+1 weights into the alternate buffer (issue-early)
        if (tap < 8) {
            const u16* nw = wrb + (size_t)(tap + 1) * 16384;
            if ((tap & 1) == 0) {
#pragma unroll
                for (int ks = 0; ks < 4; ++ks) {
                    awB[0][ks] = *(const short8*)(nw + ks * 1024);
                    awB[1][ks] = *(const short8*)(nw + ks * 1024 + 512);
                }
            } else {
#pragma unroll
                for (int ks = 0; ks < 4; ++ks) {
                    awA[0][ks] = *(const short8*)(nw + ks * 1024);
                    awA[1][ks] = *(const short8*)(nw + ks * 1024 + 512);
                }
            }
        }

#pragma unroll
        for (int ks = 0; ks < 4; ++ks) {
            int sl = ks * 4 + q;                 // logical k-segment
            short8 bf[4];
#pragma unroll
            for (int nt = 0; nt < 4; ++nt) {
                int row = rbase + nt * 16;
                short8 v = *(const short8*)&Xh[row * 128
                                               + ((sl + row) & 15) * 8];
                bf[nt] = ((nt & 1) ? inv_o : inv_e) ? (short8)0 : v;
            }
            __builtin_amdgcn_s_setprio(1);       // T5: favor MFMA cluster
#pragma unroll
            for (int mt = 0; mt < 2; ++mt) {
                short8 a = ((tap & 1) == 0) ? awA[mt][ks] : awB[mt][ks];
#pragma unroll
                for (int nt = 0; nt < 4; ++nt)
                    acc[mt][nt] = __builtin_amdgcn_mfma_f32_16x16x32_bf16(
                        a, bf[nt], acc[mt][nt], 0, 0, 0);
            }
            __builtin_amdgcn_s_setprio(0);
        }
    }

    // ---- epilogue: convF[z][co16][pix16][lane][4] f16 + stats (fp32) ----
    float s = 0.f, s2 = 0.f;
    int z = j * NB + b;
    int co16b  = coh * 4 + (w & 1) * 2;     // cobase>>4
    int pix16b = pt * 8 + (w >> 1) * 4;     // (p0+pixbase)>>4
#pragma unroll
    for (int mt = 0; mt < 2; ++mt) {
#pragma unroll
        for (int nt = 0; nt < 4; ++nt) {
            f32x4 v = acc[mt][nt];
            u16 ev[4];
#pragma unroll
            for (int r = 0; r < 4; ++r) {
                float val = v[r];
                ev[r] = f2h(val);
                s += val;
                s2 = fmaf(val, val, s2);
            }
            uint2 pw;
            __builtin_memcpy(&pw, ev, 8);
            size_t addr = (size_t)z * 131072
                        + (size_t)(co16b + mt) * 16384
                        + (size_t)(pix16b + nt) * 256 + lane * 4;
            *(uint2*)&conv_out[addr] = pw;
        }
    }
#pragma unroll
    for (int off = 32; off; off >>= 1) {
        s  += __shfl_down(s,  (unsigned)off, 64);
        s2 += __shfl_down(s2, (unsigned)off, 64);
    }
    if (lane == 0) {
        atomicAdd(&stats[(j * NB + b) * 2 + 0], s);
        atomicAdd(&stats[(j * NB + b) * 2 + 1], s2);
    }
}

// ---------------------------------------------------------------------------
// norm_kernel: GroupNorm(1) + exact GELU. Reads fragment-order convF
// (proven r12); q/k store packed uint2; v path 4 stride-1024 scalars.
// ---------------------------------------------------------------------------
__global__ __launch_bounds__(256) void norm_kernel(
        const void* __restrict__ xdet,
        const u16* __restrict__ convF, const float* __restrict__ stats,
        const void* __restrict__ g0, const void* __restrict__ b0,
        const void* __restrict__ g1, const void* __restrict__ b1,
        const void* __restrict__ g2, const void* __restrict__ b2,
        u16* __restrict__ qh, u16* __restrict__ kh, u16* __restrict__ vh) {
    int isf = detect_isf(xdet);
    int t = threadIdx.x;
    int x = blockIdx.x;              // pix16 group (0..3), 256 pixels
    int h = blockIdx.y;
    int z = blockIdx.z;
    int j = z >> 4;
    int b = z & 15;
    const void* gam = (j == 0) ? g0 : ((j == 1) ? g1 : g2);
    const void* bet = (j == 0) ? b0 : ((j == 1) ? b1 : b2);

    float sum = stats[z * 2], ss = stats[z * 2 + 1];
    const float inv = 1.0f / 131072.0f;
    float mean = sum * inv;
    float var  = fmaxf(ss * inv - mean * mean, 0.f);
    float rstd = rsqrtf(var + 1e-6f);

    int lane = t & 63, fi = t >> 6;      // 4 fragments per pass
    int q2 = lane >> 4, l16 = lane & 15;

    const size_t zbase = (size_t)z * 131072;
    u16* qkdst = ((j == 0) ? qh : kh) + ((size_t)(b * NH + h)) * NPIX * DH;
    u16* vdst  = vh + ((size_t)(b * NH + h)) * DH * NPIX;

#pragma unroll
    for (int p = 0; p < 8; ++p) {
        int fgi   = p * 4 + fi;          // 0..31
        int co16l = fgi >> 4;            // 0..1
        int pix16l = fgi & 15;           // 0..15
        int co16  = h * 2 + co16l;
        int pix16 = x * 16 + pix16l;
        const u16* src = convF + zbase + (size_t)co16 * 16384
                       + (size_t)pix16 * 256 + lane * 4;
        uint2 wv = *(const uint2*)src;
        u16 ev[4];
        __builtin_memcpy(ev, &wv, 8);

        int cl0 = co16l * 16 + q2 * 4;   // channel within head (0..31), 4 run
        int pix = pix16 * 16 + l16;      // global pixel 0..1023

        float o[4];
#pragma unroll
        for (int r = 0; r < 4; ++r) {
            float v = h2f(ev[r]);
            v = (v - mean) * rstd * loadf(gam, h * DH + cl0 + r, isf)
              + loadf(bet, h * DH + cl0 + r, isf);
            o[r] = 0.5f * v * (1.0f + erff(v * 0.70710678118654752f));
        }

        if (j == 2) {
#pragma unroll
            for (int r = 0; r < 4; ++r)
                vdst[(size_t)(cl0 + r) * NPIX + pix] = f2h(o[r]);
        } else {
            uint2 pw = make_uint2((u32)pk_h2(o[0], o[1]),
                                  (u32)pk_h2(o[2], o[3]));
            *(uint2*)(qkdst + (size_t)pix * DH + cl0) = pw;
        }
    }
}

// ---------------------------------------------------------------------------
// attn2: MFMA flash attention (r8 geometry + r11 zero-bpermute PV + r13
// attfB epilogue + r14 T5 setprio).
// ---------------------------------------------------------------------------
__global__ __launch_bounds__(256) void attn2_kernel(
        const u16* __restrict__ qh, const u16* __restrict__ kh,
        const u16* __restrict__ vh, const u16* __restrict__ biasT,
        u16* __restrict__ attfh) {
    __shared__ __align__(16) u16 Kl[2][128 * 40];   // 20,480 B (80B rows)
    __shared__ __align__(16) u16 Vl[2][32 * 136];   // 17,408 B (272B rows)

    int t = threadIdx.x;
    int f = blockIdx.x;
    int r_ = f >> 3;
    int g = (f & 7) * 4 + (r_ >> 4);     // g = qt*4 + h
    int b = r_ & 15;
    int h = g & 3, qt = g >> 2;          // qt 0..7
    int w = t >> 6, lane = t & 63, q = lane >> 4, l16 = lane & 15;
    int nrow0 = qt * 128 + w * 32;

    const u16* qb = qh + (((size_t)(b * NH + h)) * NPIX) * DH;
    const u16* kb = kh + (((size_t)(b * NH + h)) * NPIX) * DH;
    const u16* vb = vh + (((size_t)(b * NH + h)) * DH) * NPIX;
    // fragment-order bias bases: biasC[h][n16][m16][lane][r]
    const u16* bf0 = biasT + ((size_t)h << 20)
                   + ((size_t)(qt * 8 + w * 2 + 0) << 14) + lane * 4;
    const u16* bf1 = biasT + ((size_t)h << 20)
                   + ((size_t)(qt * 8 + w * 2 + 1) << 14) + lane * 4;

    // stage coords: K tile 8KB contiguous (rows 64B), V tile 32 rows x 256B
    int krow = t >> 2, kseg = t & 3;
    int vrow = t >> 4, vseg = t & 15;

    // ---- prologue: stage tile 0 into buf 0 ----
    {
        uint4 k0 = *(const uint4*)(kb + t * 8);
        uint4 k1 = *(const uint4*)(kb + (t + 256) * 8);
        uint4 v0 = *(const uint4*)(vb + vrow * NPIX + vseg * 8);
        uint4 v1 = *(const uint4*)(vb + (vrow + 16) * NPIX + vseg * 8);
        *(uint4*)&Kl[0][krow * 40 + kseg * 8] = k0;
        *(uint4*)&Kl[0][(krow + 64) * 40 + kseg * 8] = k1;
        *(uint4*)&Vl[0][vrow * 136 + vseg * 8] = v0;
        *(uint4*)&Vl[0][(vrow + 16) * 136 + vseg * 8] = v1;
    }

    half8 qf[2];
#pragma unroll
    for (int nt = 0; nt < 2; ++nt)
        qf[nt] = *(const half8*)(qb + (size_t)(nrow0 + nt * 16 + l16) * DH
                                 + q * 8);

    f32x4 O[2][2];   // [dt][nt], O^T C-layout: col n=l16, row d=q*4+reg
#pragma unroll
    for (int dt = 0; dt < 2; ++dt)
#pragma unroll
        for (int nt = 0; nt < 2; ++nt) O[dt][nt] = (f32x4)0.f;
    float mrow[2] = {-1e30f, -1e30f}, lrow[2] = {0.f, 0.f};

    __syncthreads();

    for (int kc = 0; kc < 8; ++kc) {
        int cur = kc & 1;
        const u16* Kc = &Kl[cur][0];
        const u16* Vc = &Vl[cur][0];

        // T14 issue-early: prefetch tile kc+1 into regs (write after compute)
        uint4 pk0, pk1, pv0, pv1;
        bool pf = (kc < 7);
        if (pf) {
            int m0n = (kc + 1) * 128;
            pk0 = *(const uint4*)(kb + m0n * 32 + t * 8);
            pk1 = *(const uint4*)(kb + m0n * 32 + (t + 256) * 8);
            pv0 = *(const uint4*)(vb + vrow * NPIX + m0n + vseg * 8);
            pv1 = *(const uint4*)(vb + (vrow + 16) * NPIX + m0n + vseg * 8);
        }

        // ---- QK^T + bias via MFMA C-operand (T5 prio around cluster) ----
        f32x4 St[8][2];
        __builtin_amdgcn_s_setprio(1);
#pragma unroll
        for (int mt = 0; mt < 8; ++mt) {
            half8 kf = *(const half8*)&Kc[(mt * 16 + l16) * 40 + q * 8];
            int m16 = kc * 8 + mt;
            ushort4 bv0 = *(const ushort4*)(bf0 + (m16 << 8));
            ushort4 bv1 = *(const ushort4*)(bf1 + (m16 << 8));
            f32x4 c0, c1;
            c0[0] = bf2f(bv0.x); c0[1] = bf2f(bv0.y);
            c0[2] = bf2f(bv0.z); c0[3] = bf2f(bv0.w);
            c1[0] = bf2f(bv1.x); c1[1] = bf2f(bv1.y);
            c1[2] = bf2f(bv1.z); c1[3] = bf2f(bv1.w);
            St[mt][0] = __builtin_amdgcn_mfma_f32_16x16x32_f16(
                kf, qf[0], c0, 0, 0, 0);
            St[mt][1] = __builtin_amdgcn_mfma_f32_16x16x32_f16(
                kf, qf[1], c1, 0, 0, 0);
        }
        __builtin_amdgcn_s_setprio(0);
        float mx[2] = {-1e30f, -1e30f};
#pragma unroll
        for (int mt = 0; mt < 8; ++mt)
#pragma unroll
            for (int nt = 0; nt < 2; ++nt)
#pragma unroll
                for (int r = 0; r < 4; ++r)
                    mx[nt] = fmaxf(mx[nt], St[mt][nt][r]);
        float alpha[2];
#pragma unroll
        for (int nt = 0; nt < 2; ++nt) {
            mx[nt] = fmaxf(mx[nt], __shfl_xor(mx[nt], 16, 64));
            mx[nt] = fmaxf(mx[nt], __shfl_xor(mx[nt], 32, 64));
            float mn = fmaxf(mrow[nt], mx[nt]);
            alpha[nt] = __expf(mrow[nt] - mn);
            mrow[nt] = mn;
        }
        float sm[2] = {0.f, 0.f};
#pragma unroll
        for (int mt = 0; mt < 8; ++mt)
#pragma unroll
            for (int nt = 0; nt < 2; ++nt)
#pragma unroll
                for (int r = 0; r < 4; ++r) {
                    float p = __expf(St[mt][nt][r] - mrow[nt]);
                    St[mt][nt][r] = p;
                    sm[nt] += p;
                }
#pragma unroll
        for (int nt = 0; nt < 2; ++nt) {
            sm[nt] += __shfl_xor(sm[nt], 16, 64);
            sm[nt] += __shfl_xor(sm[nt], 32, 64);
            lrow[nt] = lrow[nt] * alpha[nt] + sm[nt];
        }
        if (!__all(alpha[0] == 1.0f && alpha[1] == 1.0f)) {
#pragma unroll
            for (int dt = 0; dt < 2; ++dt)
#pragma unroll
                for (int nt = 0; nt < 2; ++nt)
#pragma unroll
                    for (int r = 0; r < 4; ++r)
                        O[dt][nt][r] *= alpha[nt];
        }
        // ---- PV, zero-shuffle (permuted-k): lane's own pk_h2 words are
        // its B-fragment; V consumed at matching offsets q*4 / 16+q*4 ----
        __builtin_amdgcn_s_setprio(1);
#pragma unroll
        for (int ms = 0; ms < 4; ++ms) {
            half8 vf[2];
#pragma unroll
            for (int dt = 0; dt < 2; ++dt) {
                const u16* vrow_p = &Vc[(dt * 16 + l16) * 136 + ms * 32];
                uint2 lo = *(const uint2*)(vrow_p + q * 4);
                uint2 hi = *(const uint2*)(vrow_p + 16 + q * 4);
                uint4 cmb = make_uint4(lo.x, lo.y, hi.x, hi.y);
                __builtin_memcpy(&vf[dt], &cmb, 16);
            }
#pragma unroll
            for (int nt = 0; nt < 2; ++nt) {
                int pw[4];
                pw[0] = pk_h2(St[2 * ms][nt][0],     St[2 * ms][nt][1]);
                pw[1] = pk_h2(St[2 * ms][nt][2],     St[2 * ms][nt][3]);
                pw[2] = pk_h2(St[2 * ms + 1][nt][0], St[2 * ms + 1][nt][1]);
                pw[3] = pk_h2(St[2 * ms + 1][nt][2], St[2 * ms + 1][nt][3]);
                half8 pf2; __builtin_memcpy(&pf2, pw, 16);
#pragma unroll
                for (int dt = 0; dt < 2; ++dt)
                    O[dt][nt] = __builtin_amdgcn_mfma_f32_16x16x32_f16(
                        vf[dt], pf2, O[dt][nt], 0, 0, 0);
            }
        }
        __builtin_amdgcn_s_setprio(0);
        // ---- write prefetched tile into the alternate buffer ----
        if (pf) {
            *(uint4*)&Kl[cur ^ 1][krow * 40 + kseg * 8] = pk0;
            *(uint4*)&Kl[cur ^ 1][(krow + 64) * 40 + kseg * 8] = pk1;
            *(uint4*)&Vl[cur ^ 1][vrow * 136 + vseg * 8] = pv0;
            *(uint4*)&Vl[cur ^ 1][(vrow + 16) * 136 + vseg * 8] = pv1;
        }
        __syncthreads();
    }

    // ---- epilogue: attfB[b][pix16][ks=h][lane][8] f16, coalesced 16B ----
    int pix16b = nrow0 >> 4;             // qt*8 + w*2
#pragma unroll
    for (int nt = 0; nt < 2; ++nt) {
        float rl = 1.0f / lrow[nt];
        f32x4 o0 = O[0][nt], o1 = O[1][nt];
        uint4 pw = make_uint4((u32)pk_h2(o0[0] * rl, o0[1] * rl),
                              (u32)pk_h2(o0[2] * rl, o0[3] * rl),
                              (u32)pk_h2(o1[0] * rl, o1[1] * rl),
                              (u32)pk_h2(o1[2] * rl, o1[3] * rl));
        *(uint4*)&attfh[(((size_t)(b * 64 + pix16b + nt) * 4 + h) << 9)
                        + lane * 8] = pw;
    }
}

// ---------------------------------------------------------------------------
// out3: MFMA 1x1 conv + bias. B-operand from attfB (coalesced, r13);
// WfF k-permuted. Round 15: T5 setprio around the MFMA cluster
// (independent blocks, no K-loop barriers).
// 512 blocks = 2 blocks/CU. Wave = 32co x 32pix, acc 2x2.
// ---------------------------------------------------------------------------
__global__ __launch_bounds__(256) void out3_kernel(
        const void* __restrict__ xdet,
        const u16* __restrict__ attfB, const u16* __restrict__ Wf,
        const void* __restrict__ ob, void* __restrict__ out) {
    int isf = detect_isf(xdet);
    int t = threadIdx.x;
    int n0 = blockIdx.x * 64, b = blockIdx.y, zc = blockIdx.z;
    int w = t >> 6, lane = t & 63, q = lane >> 4, l16 = lane & 15;
    int cobase = zc * 64 + (w & 1) * 32, nbase = (w >> 1) * 32;
    int p16b = (n0 + nbase) >> 4;

    f32x4 acc[2][2];
#pragma unroll
    for (int mt = 0; mt < 2; ++mt)
#pragma unroll
        for (int nt = 0; nt < 2; ++nt) acc[mt][nt] = (f32x4)0.f;

    const u16* wfb = Wf + (zc * 2 + (w & 1)) * 4096 + lane * 8;
#pragma unroll
    for (int ks = 0; ks < 4; ++ks) {
        half8 a[2], bfr[2];
#pragma unroll
        for (int mt = 0; mt < 2; ++mt)
            a[mt] = *(const half8*)(wfb + ks * 1024 + mt * 512);
#pragma unroll
        for (int nt = 0; nt < 2; ++nt)
            bfr[nt] = *(const half8*)&attfB[
                (((size_t)(b * 64 + p16b + nt) * 4 + ks) << 9) + lane * 8];
        __builtin_amdgcn_s_setprio(1);
#pragma unroll
        for (int mt = 0; mt < 2; ++mt)
#pragma unroll
            for (int nt = 0; nt < 2; ++nt)
                acc[mt][nt] = __builtin_amdgcn_mfma_f32_16x16x32_f16(
                    a[mt], bfr[nt], acc[mt][nt], 0, 0, 0);
        __builtin_amdgcn_s_setprio(0);
    }

#pragma unroll
    for (int mt = 0; mt < 2; ++mt) {
#pragma unroll
        for (int nt = 0; nt < 2; ++nt) {
            f32x4 v = acc[mt][nt];
            int n = n0 + nbase + nt * 16 + l16;
#pragma unroll
            for (int r = 0; r < 4; ++r) {
                int co = cobase + mt * 16 + q * 4 + r;
                float val = v[r] + loadf(ob, co, isf);
                size_t oidx = ((size_t)b * NC + co) * NPIX + n;
                if (isf) ((float*)out)[oidx] = val;
                else     ((u16*)out)[oidx]   = f2bf(val);
            }
        }
    }
}

// ---------------------------------------------------------------------------
// Workspace (peak ~48 MiB). All inter-kernel tensors fragment-ordered
// (r5/r6/r12/r13):
//   [0,448) stats (zeroed by prep_all block 0) | [448,512) pad
//   regQ = ws+512 (25,165,824 B):
//     xTp  bf16 4,718,592 B  @Q+0          (prep_all -> conv6; dead after)
//     WtF  bf16   884,736 B  @Q+5242880    (prep_all -> conv6; dead after)
//     qh/kh/vh f16 4 MB each @Q+0/4M/8M    (norm -> attn2; overwrite xTp/Wt)
//     biasC bf16 8 MB        @Q+12582912   (prep_all -> attn2)  [12M,20M)
//     WfF   f16 32 KB        @Q+20971520   (prep_all -> out3, k-permuted)
//   regA = regQ+25165824 (25,165,824 B):
//     convF f16 12.58 MB                   (conv6 -> norm; dead after)
//     attfB f16 4 MB @A+16777216           (attn2 -> out3, B-fragment order)
// 5 dispatches: prep_all -> conv6 -> norm -> attn2 -> out3
// ---------------------------------------------------------------------------
extern "C" void kernel_launch(void* const* d_in, const int* in_sizes, int n_in,
                              void* d_out, int out_size, void* d_ws,
                              size_t ws_size, hipStream_t stream) {
    (void)in_sizes; (void)n_in; (void)out_size; (void)ws_size;
    const void* x     = d_in[0];
    const void* wq    = d_in[1];
    const void* gq    = d_in[2];
    const void* bq    = d_in[3];
    const void* wk    = d_in[4];
    const void* gk    = d_in[5];
    const void* bk    = d_in[6];
    const void* wv    = d_in[7];
    const void* gv    = d_in[8];
    const void* bv    = d_in[9];
    const void* table = d_in[10];
    const int*  rel   = (const int*)d_in[11];
    const void* ow    = d_in[12];
    const void* ob    = d_in[13];

    char* ws = (char*)d_ws;
    float* stats = (float*)(ws);
    char*  regQ  = ws + 512;
    u16*   xTp   = (u16*)regQ;                       // padded, 4,718,592 B
    u16*   Wt    = (u16*)(regQ + 5242880);
    u16*   qhp   = (u16*)regQ;                       // alias after conv6
    u16*   khp   = (u16*)(regQ + 4194304);
    u16*   vhp   = (u16*)(regQ + 8388608);
    u16*   biasT = (u16*)(regQ + 12582912);          // prep_all -> attn2
    u16*   Wf    = (u16*)(regQ + 20971520);          // prep_all -> out3
    char*  regA  = regQ + 25165824;
    u16*   conv  = (u16*)regA;                       // conv6 -> norm (f16)
    u16*   attfh = (u16*)(regA + 16777216);          // attn2 -> out3 (f16)

    prep_all<<<1024, 256, 0, stream>>>(x, wq, wk, wv, ow, rel, table,
                                       Wt, Wf, xTp, biasT, stats);
    conv6_kernel<<<dim3(16, 16, 3), 256, 0, stream>>>(xTp, Wt, conv, stats);
    norm_kernel<<<dim3(4, 4, 48), 256, 0, stream>>>(x, conv, stats,
                                                    gq, bq, gk, bk, gv, bv,
                                                    qhp, khp, vhp);
    attn2_kernel<<<512, 256, 0, stream>>>(qhp, khp, vhp, biasT, attfh);
    out3_kernel<<<dim3(16, 16, 2), 256, 0, stream>>>(x, attfh, Wf, ob, d_out);
}

// Round 16
// 179.422 us; speedup vs baseline: 1.0110x; 1.0110x over previous
//
#include <hip/hip_runtime.h>

typedef unsigned short u16;
typedef unsigned int   u32;

#define NB   16      // batch
#define NC   128     // channels
#define NPIX 1024    // 32*32
#define NH   4       // heads
#define DH   32      // dim head

typedef __attribute__((ext_vector_type(8))) short short8;
typedef __attribute__((ext_vector_type(4))) float f32x4;
typedef __attribute__((ext_vector_type(8))) _Float16 half8;

#define XROWS 1152   // 64 guard + 1024 + 64 guard rows per batch in xTp

__device__ __forceinline__ float bf2f(u16 u) {
    return __uint_as_float(((u32)u) << 16);
}
__device__ __forceinline__ u16 f2bf(float f) {
    u32 u = __float_as_uint(f);
    u32 r = (u + 0x7fffu + ((u >> 16) & 1u)) >> 16;
    return (u16)r;
}
__device__ __forceinline__ u16 f2h(float f) {
    _Float16 h = (_Float16)f;
    u16 r; __builtin_memcpy(&r, &h, 2); return r;
}
__device__ __forceinline__ float h2f(u16 u) {
    _Float16 h; __builtin_memcpy(&h, &u, 2); return (float)h;
}
__device__ __forceinline__ int pk_h2(float a, float b) {
    auto h = __builtin_amdgcn_cvt_pkrtz(a, b);   // __fp16 ext_vector(2)
    int r; __builtin_memcpy(&r, &h, 4); return r;
}
// dtype-agnostic loads: isf=1 -> fp32 data, isf=0 -> bf16 data
__device__ __forceinline__ float loadf(const void* p, int i, int isf) {
    return isf ? ((const float*)p)[i] : bf2f(((const u16*)p)[i]);
}
__device__ __forceinline__ float4 load4(const void* p, int i4, int isf) {
    if (isf) return ((const float4*)p)[i4];
    ushort4 u = ((const ushort4*)p)[i4];
    return make_float4(bf2f(u.x), bf2f(u.y), bf2f(u.z), bf2f(u.w));
}
// Per-wave dtype self-detect (replaces detect_kernel dispatch).
// fp32 N(0,1) data: the 32 low-mantissa halfwords in x[0..63] hit exp>=134
// with P~0.48 each (P(no hit)=0.52^32~8e-10, identical for every wave since
// all read the same words). bf16 N(0,1): |x|<128 -> exp<134 always.
__device__ __forceinline__ int detect_isf(const void* x) {
    const u16* p = (const u16*)x;
    u16 v = p[threadIdx.x & 63];
    int e = (v >> 7) & 0xFF;
    unsigned long long m = __ballot(e >= 134);
    return m != 0ull ? 1 : 0;
}

// ---------------------------------------------------------------------------
// prep_all: fused prep. 1D grid of 1024 blocks (r14 coalesced weight read):
//   [0,192):    WtF  (192 blocks x 256 = 49,152 (j,co,ci); 9 taps each)
//   [192,256):  WfF  (16,384 elements, k-permuted — r13)
//   [256,768):  xTp transpose + guard zeroing (8 pixg x 4 cig x 16 b)
//   [768,1024): biasC fragment-order gather (16 nt x 16 mt)
// ---------------------------------------------------------------------------
__global__ __launch_bounds__(256) void prep_all(
        const void* __restrict__ x,
        const void* __restrict__ w0, const void* __restrict__ w1,
        const void* __restrict__ w2, const void* __restrict__ ow,
        const int* __restrict__ rel, const void* __restrict__ table,
        u16* __restrict__ Wt, u16* __restrict__ Wf, u16* __restrict__ xTp,
        u16* __restrict__ biasT, float* __restrict__ stats) {
    __shared__ __align__(16) u32 smem_u[4160];   // 16,640 B union
    int isf = detect_isf(x);
    int bid = blockIdx.x;
    int t = threadIdx.x;

    if (bid < 192) {
        // ---- WtF: coalesced 9-tap read per (j,co,ci) + stats zeroing ----
        if (bid == 0 && t < 96) stats[t] = 0.f;
        int g = bid * 256 + t;            // 0..49151
        int j  = g >> 14;                 // 0..2
        int cc = g & 16383;
        int co = cc >> 7, ci = cc & 127;
        const void* w = (j == 0) ? w0 : ((j == 1) ? w1 : w2);
        int coh = (co >> 6) & 1, wm = (co >> 5) & 1;
        int mt  = (co >> 4) & 1, l16 = co & 15;
        int ks  = (ci >> 5) & 3, q  = (ci >> 3) & 3, e = ci & 7;
        int dstbase = (coh * 2 + wm) * 4096 + ks * 1024 + mt * 512
                    + (q * 16 + l16) * 8 + e;
        int src0 = (co * 128 + ci) * 9;   // 9 contiguous floats follow
#pragma unroll
        for (int tap = 0; tap < 9; ++tap) {
            float v = loadf(w, src0 + tap, isf);
            Wt[(j * 9 + tap) * 16384 + dstbase] = f2bf(v);
        }
    } else if (bid < 256) {
        // ---- WfF (k-permuted for attfB, r13) ----
        int i2 = (bid - 192) * 256 + t;   // 0..16383
        int co = i2 >> 7, k = i2 & 127;
        int zc = (co >> 6) & 1, wm = (co >> 5) & 1;
        int mt = (co >> 4) & 1, l16 = co & 15;
        int ks = k >> 5, c = k & 31;
        // inverse of pi: channel c -> fragment slot (qf, ef)
        int qf, ef;
        if (c < 16) { qf = c >> 2;        ef = c & 3; }
        else        { qf = (c - 16) >> 2; ef = 4 + ((c - 16) & 3); }
        int dst = (zc * 2 + wm) * 4096 + ks * 1024 + mt * 512
                + (qf * 16 + l16) * 8 + ef;
        Wf[dst] = f2h(loadf(ow, i2, isf));
    } else if (bid < 768) {
        // ---- xTp transpose + guard zeroing (proven prep_x) ----
        float* tile = (float*)smem_u;            // 32*129 floats
        int b2 = bid - 256;
        int pixg = b2 & 7, cig = (b2 >> 3) & 3, b = b2 >> 5;

        if (pixg == 0 || pixg == 7) {
            int row = (pixg == 0 ? 0 : 1088) + (t >> 2);
            int seg = t & 3;
            size_t dst = ((size_t)(b * XROWS + row)) * 128 + cig * 32 + seg * 8;
            *(uint4*)&xTp[dst] = make_uint4(0, 0, 0, 0);
        }

        int ci = t >> 3, px0 = (t & 7) * 16;
        int base = b * (NC * NPIX) + (cig * 32 + ci) * NPIX + pixg * 128 + px0;
#pragma unroll
        for (int u = 0; u < 4; ++u) {
            float4 v = load4(x, (base >> 2) + u, isf);
            float* d = &tile[ci * 129 + px0 + u * 4];
            d[0] = v.x; d[1] = v.y; d[2] = v.z; d[3] = v.w;
        }
        __syncthreads();
#pragma unroll
        for (int u = 0; u < 2; ++u) {
            int c = t + u * 256;
            int pix = c >> 2, seg = c & 3;
            u16 tmp[8];
#pragma unroll
            for (int e = 0; e < 8; ++e)
                tmp[e] = f2bf(tile[(seg * 8 + e) * 129 + pix]);
            size_t dst = ((size_t)(b * XROWS + 64 + pixg * 128 + pix)) * 128
                       + cig * 32 + seg * 8;
            *(ushort4*)&xTp[dst] =
                make_ushort4(tmp[0], tmp[1], tmp[2], tmp[3]);
            *(ushort4*)&xTp[dst + 4] =
                make_ushort4(tmp[4], tmp[5], tmp[6], tmp[7]);
        }
    } else {
        // ---- biasC fragment-order gather; one float4 per (n,m) pair ----
        int* rl = (int*)smem_u;                  // 64*65 ints
        int b2 = bid - 768;
        int nt = b2 & 15, mt = b2 >> 4;

#pragma unroll
        for (int c = 0; c < 16; ++c) {
            int i = t + c * 256;              // 4096
            int r = i >> 6, cc = i & 63;      // r=n-local, cc=m-local
            rl[r * 65 + cc] = rel[(size_t)(nt * 64 + r) * 1024 + mt * 64 + cc];
        }
        __syncthreads();

#pragma unroll
        for (int c = 0; c < 16; ++c) {
            int wdx = t + c * 256;            // 0..4095
            int r     = wdx & 3;
            int lane  = (wdx >> 2) & 63;
            int fragl = wdx >> 8;             // 0..15
            int n16l  = fragl >> 2;           // 0..3
            int m16l  = fragl & 3;            // 0..3
            int n_loc = n16l * 16 + (lane & 15);
            int m_loc = m16l * 16 + ((lane >> 4) << 2) + r;
            int ri = rl[n_loc * 65 + m_loc];
            float4 tv = load4(table, ri, isf);   // all 4 heads (NH=4)
            float tvh[4] = {tv.x, tv.y, tv.z, tv.w};
            size_t off = ((size_t)((nt * 4 + n16l) * 64 + (mt * 4 + m16l))
                          << 8) + lane * 4 + r;
#pragma unroll
            for (int h = 0; h < NH; ++h)
                biasT[((size_t)h << 20) + off] = f2bf(tvh[h]);
        }
    }
}

// ---------------------------------------------------------------------------
// conv6: MFMA implicit-GEMM 3x3 conv, fragment-order weights (r6), convF
// output (r12). r16: setprio REVERTED (r15 measured null-to-negative —
// homogeneous waves, m190 regime). This is the proven r14 form (179.7us).
// Grid: (2coh x 8pt, 16 b, 3 j) = 768 blocks = 3 blocks/CU.
// ---------------------------------------------------------------------------
__global__ __launch_bounds__(256) void conv6_kernel(
        const u16* __restrict__ xTp, const u16* __restrict__ Wt,
        u16* __restrict__ conv_out, float* __restrict__ stats) {
    __shared__ __align__(16) u16 Xh[194 * 128];   // 49,664 B

    int t = threadIdx.x;
    int bx = blockIdx.x, b = blockIdx.y, j = blockIdx.z;
    int pt = bx >> 1, coh = bx & 1;
    int p0 = pt * 128;
    int w = t >> 6, lane = t & 63;
    int q = lane >> 4, l16 = lane & 15;
    int pixbase = (w >> 1) * 64;

    const u16* xb  = xTp + ((size_t)b * XROWS + 64) * 128;  // row 0 = pixel 0
    // fragment-order weight base for this wave: + tap*16384 + ks*1024 + mt*512
    const u16* wrb = Wt + (size_t)(j * 9) * 16384
                   + (coh * 2 + (w & 1)) * 4096 + lane * 8;

    // ---- prologue: issue tap-0 weight loads (before staging, no dep) ----
    short8 awA[2][4], awB[2][4];      // [mt][ks] double buffer
#pragma unroll
    for (int ks = 0; ks < 4; ++ks) {
        awA[0][ks] = *(const short8*)(wrb + ks * 1024);
        awA[1][ks] = *(const short8*)(wrb + ks * 1024 + 512);
    }

    // ---- stage Xh rows [p0-33, p0+161), unconditional (guard rows) ----
#pragma unroll
    for (int k = 0; k < 13; ++k) {
        int c = t + k * 256;
        if (c < 194 * 16) {
            int row = c >> 4, seg = c & 15;
            int pg = p0 - 33 + row;
            uint4 v = *(const uint4*)(xb + (size_t)pg * 128 + seg * 8);
            *(uint4*)&Xh[row * 128 + ((seg + row) & 15) * 8] = v;
        }
    }
    __syncthreads();     // the only barrier in the kernel

    f32x4 acc[2][4];
#pragma unroll
    for (int mt = 0; mt < 2; ++mt)
#pragma unroll
        for (int nt = 0; nt < 4; ++nt) acc[mt][nt] = (f32x4)0.f;

#pragma unroll
    for (int tap = 0; tap < 9; ++tap) {
        const int dy = tap / 3, dx = tap % 3;       // compile-time (unrolled)
        bool inv_e = (dx == 0) && (l16 == 0);    // nt even: px%32 == l16
        bool inv_o = (dx == 2) && (l16 == 15);   // nt odd:  px%32 == 16+l16
        int rbase = pixbase + dy * 32 + dx + l16;

        // prefetch tap+1 weights into the alternate buffer (issue-early)
        if (tap < 8) {
            const u16* nw = wrb + (size_t)(tap + 1) * 16384;
            if ((tap & 1) == 0) {
#pragma unroll
                for (int ks = 0; ks < 4; ++ks) {
                    awB[0][ks] = *(const short8*)(nw + ks * 1024);
                    awB[1][ks] = *(const short8*)(nw + ks * 1024 + 512);
                }
            } else {
#pragma unroll
                for (int ks = 0; ks < 4; ++ks) {
                    awA[0][ks] = *(const short8*)(nw + ks * 1024);
                    awA[1][ks] = *(const short8*)(nw + ks * 1024 + 512);
                }
            }
        }

#pragma unroll
        for (int ks = 0; ks < 4; ++ks) {
            int sl = ks * 4 + q;                 // logical k-segment
            short8 bf[4];
#pragma unroll
            for (int nt = 0; nt < 4; ++nt) {
                int row = rbase + nt * 16;
                short8 v = *(const short8*)&Xh[row * 128
                                               + ((sl + row) & 15) * 8];
                bf[nt] = ((nt & 1) ? inv_o : inv_e) ? (short8)0 : v;
            }
#pragma unroll
            for (int mt = 0; mt < 2; ++mt) {
                short8 a = ((tap & 1) == 0) ? awA[mt][ks] : awB[mt][ks];
#pragma unroll
                for (int nt = 0; nt < 4; ++nt)
                    acc[mt][nt] = __builtin_amdgcn_mfma_f32_16x16x32_bf16(
                        a, bf[nt], acc[mt][nt], 0, 0, 0);
            }
        }
    }

    // ---- epilogue: convF[z][co16][pix16][lane][4] f16 + stats (fp32) ----
    float s = 0.f, s2 = 0.f;
    int z = j * NB + b;
    int co16b  = coh * 4 + (w & 1) * 2;     // cobase>>4
    int pix16b = pt * 8 + (w >> 1) * 4;     // (p0+pixbase)>>4
#pragma unroll
    for (int mt = 0; mt < 2; ++mt) {
#pragma unroll
        for (int nt = 0; nt < 4; ++nt) {
            f32x4 v = acc[mt][nt];
            u16 ev[4];
#pragma unroll
            for (int r = 0; r < 4; ++r) {
                float val = v[r];
                ev[r] = f2h(val);
                s += val;
                s2 = fmaf(val, val, s2);
            }
            uint2 pw;
            __builtin_memcpy(&pw, ev, 8);
            size_t addr = (size_t)z * 131072
                        + (size_t)(co16b + mt) * 16384
                        + (size_t)(pix16b + nt) * 256 + lane * 4;
            *(uint2*)&conv_out[addr] = pw;
        }
    }
#pragma unroll
    for (int off = 32; off; off >>= 1) {
        s  += __shfl_down(s,  (unsigned)off, 64);
        s2 += __shfl_down(s2, (unsigned)off, 64);
    }
    if (lane == 0) {
        atomicAdd(&stats[(j * NB + b) * 2 + 0], s);
        atomicAdd(&stats[(j * NB + b) * 2 + 1], s2);
    }
}

// ---------------------------------------------------------------------------
// norm_kernel: GroupNorm(1) + exact GELU. Reads fragment-order convF
// (proven r12); q/k store packed uint2; v path 4 stride-1024 scalars.
// ---------------------------------------------------------------------------
__global__ __launch_bounds__(256) void norm_kernel(
        const void* __restrict__ xdet,
        const u16* __restrict__ convF, const float* __restrict__ stats,
        const void* __restrict__ g0, const void* __restrict__ b0,
        const void* __restrict__ g1, const void* __restrict__ b1,
        const void* __restrict__ g2, const void* __restrict__ b2,
        u16* __restrict__ qh, u16* __restrict__ kh, u16* __restrict__ vh) {
    int isf = detect_isf(xdet);
    int t = threadIdx.x;
    int x = blockIdx.x;              // pix16 group (0..3), 256 pixels
    int h = blockIdx.y;
    int z = blockIdx.z;
    int j = z >> 4;
    int b = z & 15;
    const void* gam = (j == 0) ? g0 : ((j == 1) ? g1 : g2);
    const void* bet = (j == 0) ? b0 : ((j == 1) ? b1 : b2);

    float sum = stats[z * 2], ss = stats[z * 2 + 1];
    const float inv = 1.0f / 131072.0f;
    float mean = sum * inv;
    float var  = fmaxf(ss * inv - mean * mean, 0.f);
    float rstd = rsqrtf(var + 1e-6f);

    int lane = t & 63, fi = t >> 6;      // 4 fragments per pass
    int q2 = lane >> 4, l16 = lane & 15;

    const size_t zbase = (size_t)z * 131072;
    u16* qkdst = ((j == 0) ? qh : kh) + ((size_t)(b * NH + h)) * NPIX * DH;
    u16* vdst  = vh + ((size_t)(b * NH + h)) * DH * NPIX;

#pragma unroll
    for (int p = 0; p < 8; ++p) {
        int fgi   = p * 4 + fi;          // 0..31
        int co16l = fgi >> 4;            // 0..1
        int pix16l = fgi & 15;           // 0..15
        int co16  = h * 2 + co16l;
        int pix16 = x * 16 + pix16l;
        const u16* src = convF + zbase + (size_t)co16 * 16384
                       + (size_t)pix16 * 256 + lane * 4;
        uint2 wv = *(const uint2*)src;
        u16 ev[4];
        __builtin_memcpy(ev, &wv, 8);

        int cl0 = co16l * 16 + q2 * 4;   // channel within head (0..31), 4 run
        int pix = pix16 * 16 + l16;      // global pixel 0..1023

        float o[4];
#pragma unroll
        for (int r = 0; r < 4; ++r) {
            float v = h2f(ev[r]);
            v = (v - mean) * rstd * loadf(gam, h * DH + cl0 + r, isf)
              + loadf(bet, h * DH + cl0 + r, isf);
            o[r] = 0.5f * v * (1.0f + erff(v * 0.70710678118654752f));
        }

        if (j == 2) {
#pragma unroll
            for (int r = 0; r < 4; ++r)
                vdst[(size_t)(cl0 + r) * NPIX + pix] = f2h(o[r]);
        } else {
            uint2 pw = make_uint2((u32)pk_h2(o[0], o[1]),
                                  (u32)pk_h2(o[2], o[3]));
            *(uint2*)(qkdst + (size_t)pix * DH + cl0) = pw;
        }
    }
}

// ---------------------------------------------------------------------------
// attn2: MFMA flash attention (r8 geometry + r11 zero-bpermute PV + r13
// attfB epilogue + r14 T5 setprio — heterogeneous wave phases, proven win).
// ---------------------------------------------------------------------------
__global__ __launch_bounds__(256) void attn2_kernel(
        const u16* __restrict__ qh, const u16* __restrict__ kh,
        const u16* __restrict__ vh, const u16* __restrict__ biasT,
        u16* __restrict__ attfh) {
    __shared__ __align__(16) u16 Kl[2][128 * 40];   // 20,480 B (80B rows)
    __shared__ __align__(16) u16 Vl[2][32 * 136];   // 17,408 B (272B rows)

    int t = threadIdx.x;
    int f = blockIdx.x;
    int r_ = f >> 3;
    int g = (f & 7) * 4 + (r_ >> 4);     // g = qt*4 + h
    int b = r_ & 15;
    int h = g & 3, qt = g >> 2;          // qt 0..7
    int w = t >> 6, lane = t & 63, q = lane >> 4, l16 = lane & 15;
    int nrow0 = qt * 128 + w * 32;

    const u16* qb = qh + (((size_t)(b * NH + h)) * NPIX) * DH;
    const u16* kb = kh + (((size_t)(b * NH + h)) * NPIX) * DH;
    const u16* vb = vh + (((size_t)(b * NH + h)) * DH) * NPIX;
    // fragment-order bias bases: biasC[h][n16][m16][lane][r]
    const u16* bf0 = biasT + ((size_t)h << 20)
                   + ((size_t)(qt * 8 + w * 2 + 0) << 14) + lane * 4;
    const u16* bf1 = biasT + ((size_t)h << 20)
                   + ((size_t)(qt * 8 + w * 2 + 1) << 14) + lane * 4;

    // stage coords: K tile 8KB contiguous (rows 64B), V tile 32 rows x 256B
    int krow = t >> 2, kseg = t & 3;
    int vrow = t >> 4, vseg = t & 15;

    // ---- prologue: stage tile 0 into buf 0 ----
    {
        uint4 k0 = *(const uint4*)(kb + t * 8);
        uint4 k1 = *(const uint4*)(kb + (t + 256) * 8);
        uint4 v0 = *(const uint4*)(vb + vrow * NPIX + vseg * 8);
        uint4 v1 = *(const uint4*)(vb + (vrow + 16) * NPIX + vseg * 8);
        *(uint4*)&Kl[0][krow * 40 + kseg * 8] = k0;
        *(uint4*)&Kl[0][(krow + 64) * 40 + kseg * 8] = k1;
        *(uint4*)&Vl[0][vrow * 136 + vseg * 8] = v0;
        *(uint4*)&Vl[0][(vrow + 16) * 136 + vseg * 8] = v1;
    }

    half8 qf[2];
#pragma unroll
    for (int nt = 0; nt < 2; ++nt)
        qf[nt] = *(const half8*)(qb + (size_t)(nrow0 + nt * 16 + l16) * DH
                                 + q * 8);

    f32x4 O[2][2];   // [dt][nt], O^T C-layout: col n=l16, row d=q*4+reg
#pragma unroll
    for (int dt = 0; dt < 2; ++dt)
#pragma unroll
        for (int nt = 0; nt < 2; ++nt) O[dt][nt] = (f32x4)0.f;
    float mrow[2] = {-1e30f, -1e30f}, lrow[2] = {0.f, 0.f};

    __syncthreads();

    for (int kc = 0; kc < 8; ++kc) {
        int cur = kc & 1;
        const u16* Kc = &Kl[cur][0];
        const u16* Vc = &Vl[cur][0];

        // T14 issue-early: prefetch tile kc+1 into regs (write after compute)
        uint4 pk0, pk1, pv0, pv1;
        bool pf = (kc < 7);
        if (pf) {
            int m0n = (kc + 1) * 128;
            pk0 = *(const uint4*)(kb + m0n * 32 + t * 8);
            pk1 = *(const uint4*)(kb + m0n * 32 + (t + 256) * 8);
            pv0 = *(const uint4*)(vb + vrow * NPIX + m0n + vseg * 8);
            pv1 = *(const uint4*)(vb + (vrow + 16) * NPIX + m0n + vseg * 8);
        }

        // ---- QK^T + bias via MFMA C-operand (T5 prio around cluster) ----
        f32x4 St[8][2];
        __builtin_amdgcn_s_setprio(1);
#pragma unroll
        for (int mt = 0; mt < 8; ++mt) {
            half8 kf = *(const half8*)&Kc[(mt * 16 + l16) * 40 + q * 8];
            int m16 = kc * 8 + mt;
            ushort4 bv0 = *(const ushort4*)(bf0 + (m16 << 8));
            ushort4 bv1 = *(const ushort4*)(bf1 + (m16 << 8));
            f32x4 c0, c1;
            c0[0] = bf2f(bv0.x); c0[1] = bf2f(bv0.y);
            c0[2] = bf2f(bv0.z); c0[3] = bf2f(bv0.w);
            c1[0] = bf2f(bv1.x); c1[1] = bf2f(bv1.y);
            c1[2] = bf2f(bv1.z); c1[3] = bf2f(bv1.w);
            St[mt][0] = __builtin_amdgcn_mfma_f32_16x16x32_f16(
                kf, qf[0], c0, 0, 0, 0);
            St[mt][1] = __builtin_amdgcn_mfma_f32_16x16x32_f16(
                kf, qf[1], c1, 0, 0, 0);
        }
        __builtin_amdgcn_s_setprio(0);
        float mx[2] = {-1e30f, -1e30f};
#pragma unroll
        for (int mt = 0; mt < 8; ++mt)
#pragma unroll
            for (int nt = 0; nt < 2; ++nt)
#pragma unroll
                for (int r = 0; r < 4; ++r)
                    mx[nt] = fmaxf(mx[nt], St[mt][nt][r]);
        float alpha[2];
#pragma unroll
        for (int nt = 0; nt < 2; ++nt) {
            mx[nt] = fmaxf(mx[nt], __shfl_xor(mx[nt], 16, 64));
            mx[nt] = fmaxf(mx[nt], __shfl_xor(mx[nt], 32, 64));
            float mn = fmaxf(mrow[nt], mx[nt]);
            alpha[nt] = __expf(mrow[nt] - mn);
            mrow[nt] = mn;
        }
        float sm[2] = {0.f, 0.f};
#pragma unroll
        for (int mt = 0; mt < 8; ++mt)
#pragma unroll
            for (int nt = 0; nt < 2; ++nt)
#pragma unroll
                for (int r = 0; r < 4; ++r) {
                    float p = __expf(St[mt][nt][r] - mrow[nt]);
                    St[mt][nt][r] = p;
                    sm[nt] += p;
                }
#pragma unroll
        for (int nt = 0; nt < 2; ++nt) {
            sm[nt] += __shfl_xor(sm[nt], 16, 64);
            sm[nt] += __shfl_xor(sm[nt], 32, 64);
            lrow[nt] = lrow[nt] * alpha[nt] + sm[nt];
        }
        if (!__all(alpha[0] == 1.0f && alpha[1] == 1.0f)) {
#pragma unroll
            for (int dt = 0; dt < 2; ++dt)
#pragma unroll
                for (int nt = 0; nt < 2; ++nt)
#pragma unroll
                    for (int r = 0; r < 4; ++r)
                        O[dt][nt][r] *= alpha[nt];
        }
        // ---- PV, zero-shuffle (permuted-k): lane's own pk_h2 words are
        // its B-fragment; V consumed at matching offsets q*4 / 16+q*4 ----
        __builtin_amdgcn_s_setprio(1);
#pragma unroll
        for (int ms = 0; ms < 4; ++ms) {
            half8 vf[2];
#pragma unroll
            for (int dt = 0; dt < 2; ++dt) {
                const u16* vrow_p = &Vc[(dt * 16 + l16) * 136 + ms * 32];
                uint2 lo = *(const uint2*)(vrow_p + q * 4);
                uint2 hi = *(const uint2*)(vrow_p + 16 + q * 4);
                uint4 cmb = make_uint4(lo.x, lo.y, hi.x, hi.y);
                __builtin_memcpy(&vf[dt], &cmb, 16);
            }
#pragma unroll
            for (int nt = 0; nt < 2; ++nt) {
                int pw[4];
                pw[0] = pk_h2(St[2 * ms][nt][0],     St[2 * ms][nt][1]);
                pw[1] = pk_h2(St[2 * ms][nt][2],     St[2 * ms][nt][3]);
                pw[2] = pk_h2(St[2 * ms + 1][nt][0], St[2 * ms + 1][nt][1]);
                pw[3] = pk_h2(St[2 * ms + 1][nt][2], St[2 * ms + 1][nt][3]);
                half8 pf2; __builtin_memcpy(&pf2, pw, 16);
#pragma unroll
                for (int dt = 0; dt < 2; ++dt)
                    O[dt][nt] = __builtin_amdgcn_mfma_f32_16x16x32_f16(
                        vf[dt], pf2, O[dt][nt], 0, 0, 0);
            }
        }
        __builtin_amdgcn_s_setprio(0);
        // ---- write prefetched tile into the alternate buffer ----
        if (pf) {
            *(uint4*)&Kl[cur ^ 1][krow * 40 + kseg * 8] = pk0;
            *(uint4*)&Kl[cur ^ 1][(krow + 64) * 40 + kseg * 8] = pk1;
            *(uint4*)&Vl[cur ^ 1][vrow * 136 + vseg * 8] = pv0;
            *(uint4*)&Vl[cur ^ 1][(vrow + 16) * 136 + vseg * 8] = pv1;
        }
        __syncthreads();
    }

    // ---- epilogue: attfB[b][pix16][ks=h][lane][8] f16, coalesced 16B ----
    int pix16b = nrow0 >> 4;             // qt*8 + w*2
#pragma unroll
    for (int nt = 0; nt < 2; ++nt) {
        float rl = 1.0f / lrow[nt];
        f32x4 o0 = O[0][nt], o1 = O[1][nt];
        uint4 pw = make_uint4((u32)pk_h2(o0[0] * rl, o0[1] * rl),
                              (u32)pk_h2(o0[2] * rl, o0[3] * rl),
                              (u32)pk_h2(o1[0] * rl, o1[1] * rl),
                              (u32)pk_h2(o1[2] * rl, o1[3] * rl));
        *(uint4*)&attfh[(((size_t)(b * 64 + pix16b + nt) * 4 + h) << 9)
                        + lane * 8] = pw;
    }
}

// ---------------------------------------------------------------------------
// out3: MFMA 1x1 conv + bias. B-operand from attfB (coalesced, r13);
// WfF k-permuted. r16: setprio reverted (r15 null). Proven r14 form.
// 512 blocks = 2 blocks/CU. Wave = 32co x 32pix, acc 2x2.
// ---------------------------------------------------------------------------
__global__ __launch_bounds__(256) void out3_kernel(
        const void* __restrict__ xdet,
        const u16* __restrict__ attfB, const u16* __restrict__ Wf,
        const void* __restrict__ ob, void* __restrict__ out) {
    int isf = detect_isf(xdet);
    int t = threadIdx.x;
    int n0 = blockIdx.x * 64, b = blockIdx.y, zc = blockIdx.z;
    int w = t >> 6, lane = t & 63, q = lane >> 4, l16 = lane & 15;
    int cobase = zc * 64 + (w & 1) * 32, nbase = (w >> 1) * 32;
    int p16b = (n0 + nbase) >> 4;

    f32x4 acc[2][2];
#pragma unroll
    for (int mt = 0; mt < 2; ++mt)
#pragma unroll
        for (int nt = 0; nt < 2; ++nt) acc[mt][nt] = (f32x4)0.f;

    const u16* wfb = Wf + (zc * 2 + (w & 1)) * 4096 + lane * 8;
#pragma unroll
    for (int ks = 0; ks < 4; ++ks) {
        half8 a[2], bfr[2];
#pragma unroll
        for (int mt = 0; mt < 2; ++mt)
            a[mt] = *(const half8*)(wfb + ks * 1024 + mt * 512);
#pragma unroll
        for (int nt = 0; nt < 2; ++nt)
            bfr[nt] = *(const half8*)&attfB[
                (((size_t)(b * 64 + p16b + nt) * 4 + ks) << 9) + lane * 8];
#pragma unroll
        for (int mt = 0; mt < 2; ++mt)
#pragma unroll
            for (int nt = 0; nt < 2; ++nt)
                acc[mt][nt] = __builtin_amdgcn_mfma_f32_16x16x32_f16(
                    a[mt], bfr[nt], acc[mt][nt], 0, 0, 0);
    }

#pragma unroll
    for (int mt = 0; mt < 2; ++mt) {
#pragma unroll
        for (int nt = 0; nt < 2; ++nt) {
            f32x4 v = acc[mt][nt];
            int n = n0 + nbase + nt * 16 + l16;
#pragma unroll
            for (int r = 0; r < 4; ++r) {
                int co = cobase + mt * 16 + q * 4 + r;
                float val = v[r] + loadf(ob, co, isf);
                size_t oidx = ((size_t)b * NC + co) * NPIX + n;
                if (isf) ((float*)out)[oidx] = val;
                else     ((u16*)out)[oidx]   = f2bf(val);
            }
        }
    }
}

// ---------------------------------------------------------------------------
// Workspace (peak ~48 MiB). All inter-kernel tensors fragment-ordered
// (r5/r6/r12/r13):
//   [0,448) stats (zeroed by prep_all block 0) | [448,512) pad
//   regQ = ws+512 (25,165,824 B):
//     xTp  bf16 4,718,592 B  @Q+0          (prep_all -> conv6; dead after)
//     WtF  bf16   884,736 B  @Q+5242880    (prep_all -> conv6; dead after)
//     qh/kh/vh f16 4 MB each @Q+0/4M/8M    (norm -> attn2; overwrite xTp/Wt)
//     biasC bf16 8 MB        @Q+12582912   (prep_all -> attn2)  [12M,20M)
//     WfF   f16 32 KB        @Q+20971520   (prep_all -> out3, k-permuted)
//   regA = regQ+25165824 (25,165,824 B):
//     convF f16 12.58 MB                   (conv6 -> norm; dead after)
//     attfB f16 4 MB @A+16777216           (attn2 -> out3, B-fragment order)
// 5 dispatches: prep_all -> conv6 -> norm -> attn2 -> out3
// Session: 213.9 -> 179.7us best (r14 config, restored here).
// ---------------------------------------------------------------------------
extern "C" void kernel_launch(void* const* d_in, const int* in_sizes, int n_in,
                              void* d_out, int out_size, void* d_ws,
                              size_t ws_size, hipStream_t stream) {
    (void)in_sizes; (void)n_in; (void)out_size; (void)ws_size;
    const void* x     = d_in[0];
    const void* wq    = d_in[1];
    const void* gq    = d_in[2];
    const void* bq    = d_in[3];
    const void* wk    = d_in[4];
    const void* gk    = d_in[5];
    const void* bk    = d_in[6];
    const void* wv    = d_in[7];
    const void* gv    = d_in[8];
    const void* bv    = d_in[9];
    const void* table = d_in[10];
    const int*  rel   = (const int*)d_in[11];
    const void* ow    = d_in[12];
    const void* ob    = d_in[13];

    char* ws = (char*)d_ws;
    float* stats = (float*)(ws);
    char*  regQ  = ws + 512;
    u16*   xTp   = (u16*)regQ;                       // padded, 4,718,592 B
    u16*   Wt    = (u16*)(regQ + 5242880);
    u16*   qhp   = (u16*)regQ;                       // alias after conv6
    u16*   khp   = (u16*)(regQ + 4194304);
    u16*   vhp   = (u16*)(regQ + 8388608);
    u16*   biasT = (u16*)(regQ + 12582912);          // prep_all -> attn2
    u16*   Wf    = (u16*)(regQ + 20971520);          // prep_all -> out3
    char*  regA  = regQ + 25165824;
    u16*   conv  = (u16*)regA;                       // conv6 -> norm (f16)
    u16*   attfh = (u16*)(regA + 16777216);          // attn2 -> out3 (f16)

    prep_all<<<1024, 256, 0, stream>>>(x, wq, wk, wv, ow, rel, table,
                                       Wt, Wf, xTp, biasT, stats);
    conv6_kernel<<<dim3(16, 16, 3), 256, 0, stream>>>(xTp, Wt, conv, stats);
    norm_kernel<<<dim3(4, 4, 48), 256, 0, stream>>>(x, conv, stats,
                                                    gq, bq, gk, bk, gv, bv,
                                                    qhp, khp, vhp);
    attn2_kernel<<<512, 256, 0, stream>>>(qhp, khp, vhp, biasT, attfh);
    out3_kernel<<<dim3(16, 16, 2), 256, 0, stream>>>(x, attfh, Wf, ob, d_out);
}